// Round 3
// baseline (180.426 us; speedup 1.0000x reference)
//
#include <hip/hip_runtime.h>
#include <math.h>
#include <stdint.h>

#ifndef TAU_CONST
#define TAU_CONST 1.0f
#endif

// ---------------- math (unchanged from round 1) ----------------

__device__ __forceinline__ void rbox_to_gauss(float x, float y, float w, float h, float r,
                                              float& mx, float& my,
                                              float& s00, float& s01, float& s11, float& det) {
    w = fminf(fmaxf(w, 1e-7f), 1e7f);
    h = fminf(fmaxf(h, 1e-7f), 1e7f);
    float a = 0.25f * w * w;   // (w/2)^2
    float b = 0.25f * h * h;   // (h/2)^2
    float s2, c2;
    __sincosf(r + r, &s2, &c2);          // sin 2r, cos 2r
    float hs = 0.5f * (a + b);
    float hd = 0.5f * (a - b);
    s00 = fmaf(hd, c2, hs);
    s11 = fmaf(-hd, c2, hs);
    s01 = hd * s2;
    det = a * b;                          // det(R S R^T) == a*b exactly
    mx = x; my = y;
}

__device__ __forceinline__ float kld_row(const float* p, const float* t) {
    float pmx, pmy, p00, p01, p11, dp;
    float tmx, tmy, t00, t01, t11, dt;
    rbox_to_gauss(p[0], p[1], p[2], p[3], p[4], pmx, pmy, p00, p01, p11, dp);
    rbox_to_gauss(t[0], t[1], t[2], t[3], t[4], tmx, tmy, t00, t01, t11, dt);
    float dx = pmx - tmx, dy = pmy - tmy;
    float inv_dt = __builtin_amdgcn_rcpf(dt);
    float inv_dp = __builtin_amdgcn_rcpf(dp);
    float term1 = (dx * dx * t11 - 2.0f * dx * dy * t01 + dy * dy * t00) * inv_dt;
    float tr = (t11 * p00 + t00 * p11 - 2.0f * t01 * p01) * inv_dt;
    float term2 = tr + __logf(dt * inv_dp);
    float dis = term1 + term2 - 2.0f;
    float kl = fmaxf(dis, 1e-6f);
    float l1p = __logf(1.0f + kl);
    return 1.0f - __builtin_amdgcn_rcpf(TAU_CONST + l1p);
}

// ---------------- persistent double-buffered pipeline ----------------
// 2048 blocks (8/CU), each grid-strides over 256-row tiles.
// LDS: 2 buffers x (pred 5120 B + tgt 5120 B) = 20480 B -> 8 blocks/CU.
// Per tile: 10 x global_load_lds width=16 (1 KB chunks, linear dest, coalesced src).
// Loop: barrier(drain cur) -> issue next-tile stage -> compute cur -> flip.
// Next tile's HBM latency hides under compute; every block keeps ~10 KB in flight.

__device__ __forceinline__ void gload_lds16(const void* g, void* l) {
    __builtin_amdgcn_global_load_lds((const __attribute__((address_space(1))) uint32_t*)g,
                                     (__attribute__((address_space(3))) uint32_t*)l,
                                     16, 0, 0);
}

#define ROWS_PER_TILE 256
#define FLOATS_PER_TILE (ROWS_PER_TILE * 5)   // 1280 floats per input per tile

__global__ void __launch_bounds__(256, 8)
gdloss_pipe_kernel(const float* __restrict__ pred,
                   const float* __restrict__ target,
                   float* __restrict__ out, int ntiles) {
    __shared__ float lds[2][2 * FLOATS_PER_TILE];  // [buf][pred 1280 | tgt 1280]
    const int tid = threadIdx.x;
    const int wv  = tid >> 6;
    const int ln  = tid & 63;
    const int stride = gridDim.x;

    int t = blockIdx.x;
    // prologue: stage first tile into buf 0
    if (t < ntiles) {
        for (int c = wv; c < 10; c += 4) {   // chunk c: c<5 pred, c>=5 tgt; dest lds[0][c*256]
            const float* g = (c < 5)
                ? (pred   + (long long)t * FLOATS_PER_TILE + c * 256 + ln * 4)
                : (target + (long long)t * FLOATS_PER_TILE + (c - 5) * 256 + ln * 4);
            gload_lds16(g, &lds[0][c * 256]);
        }
    }

    int buf = 0;
    for (; t < ntiles; t += stride) {
        __syncthreads();                     // s_waitcnt vmcnt(0) + barrier: tile t staged
        int tn = t + stride;
        if (tn < ntiles) {                   // issue next tile into buf^1 (overlaps compute)
            for (int c = wv; c < 10; c += 4) {
                const float* g = (c < 5)
                    ? (pred   + (long long)tn * FLOATS_PER_TILE + c * 256 + ln * 4)
                    : (target + (long long)tn * FLOATS_PER_TILE + (c - 5) * 256 + ln * 4);
                gload_lds16(g, &lds[buf ^ 1][c * 256]);
            }
        }
        // compute tile t: row per thread, 5 consecutive floats at 5*tid
        // bank = (5*lane + k) mod 32, gcd(5,32)=1 -> 2 lanes/bank = conflict-free
        const float* lp = &lds[buf][5 * tid];
        const float* lt = &lds[buf][FLOATS_PER_TILE + 5 * tid];
        float p[5], tt[5];
#pragma unroll
        for (int k = 0; k < 5; ++k) { p[k] = lp[k]; tt[k] = lt[k]; }
        out[(long long)t * ROWS_PER_TILE + tid] = kld_row(p, tt);
        buf ^= 1;
    }
}

// Scalar tail (rows not covered by full tiles; none at N=4M).
__global__ void gdloss_tail_kernel(const float* __restrict__ pred,
                                   const float* __restrict__ target,
                                   float* __restrict__ out, int start, int n) {
    int i = start + blockIdx.x * blockDim.x + threadIdx.x;
    if (i >= n) return;
    float p[5], t[5];
#pragma unroll
    for (int k = 0; k < 5; ++k) {
        p[k] = pred[5 * i + k];
        t[k] = target[5 * i + k];
    }
    out[i] = kld_row(p, t);
}

extern "C" void kernel_launch(void* const* d_in, const int* in_sizes, int n_in,
                              void* d_out, int out_size, void* d_ws, size_t ws_size,
                              hipStream_t stream) {
    const float* pred   = (const float*)d_in[0];
    const float* target = (const float*)d_in[1];
    float* out = (float*)d_out;
    int n      = in_sizes[0] / 5;          // rows
    int ntiles = n / ROWS_PER_TILE;
    if (ntiles > 0) {
        int blocks = ntiles < 2048 ? ntiles : 2048;   // 8 blocks/CU, persistent
        gdloss_pipe_kernel<<<blocks, 256, 0, stream>>>(pred, target, out, ntiles);
    }
    int start = ntiles * ROWS_PER_TILE;
    int rem = n - start;
    if (rem > 0) {
        int tb = (rem + 255) / 256;
        gdloss_tail_kernel<<<tb, 256, 0, stream>>>(pred, target, out, start, n);
    }
}

// Round 5
// 168.605 us; speedup vs baseline: 1.0701x; 1.0701x over previous
//
#include <hip/hip_runtime.h>
#include <math.h>
#include <stdint.h>

#ifndef TAU_CONST
#define TAU_CONST 1.0f
#endif

typedef float v2f __attribute__((ext_vector_type(2)));   // builtin vec type for NT store

// ---------------- math (unchanged) ----------------

__device__ __forceinline__ void rbox_to_gauss(float x, float y, float w, float h, float r,
                                              float& mx, float& my,
                                              float& s00, float& s01, float& s11, float& det) {
    w = fminf(fmaxf(w, 1e-7f), 1e7f);
    h = fminf(fmaxf(h, 1e-7f), 1e7f);
    float a = 0.25f * w * w;   // (w/2)^2
    float b = 0.25f * h * h;   // (h/2)^2
    float s2, c2;
    __sincosf(r + r, &s2, &c2);          // sin 2r, cos 2r
    float hs = 0.5f * (a + b);
    float hd = 0.5f * (a - b);
    s00 = fmaf(hd, c2, hs);
    s11 = fmaf(-hd, c2, hs);
    s01 = hd * s2;
    det = a * b;                          // det(R S R^T) == a*b exactly
    mx = x; my = y;
}

__device__ __forceinline__ float kld_row(const float* p, const float* t) {
    float pmx, pmy, p00, p01, p11, dp;
    float tmx, tmy, t00, t01, t11, dt;
    rbox_to_gauss(p[0], p[1], p[2], p[3], p[4], pmx, pmy, p00, p01, p11, dp);
    rbox_to_gauss(t[0], t[1], t[2], t[3], t[4], tmx, tmy, t00, t01, t11, dt);
    float dx = pmx - tmx, dy = pmy - tmy;
    float inv_dt = __builtin_amdgcn_rcpf(dt);
    float inv_dp = __builtin_amdgcn_rcpf(dp);
    float term1 = (dx * dx * t11 - 2.0f * dx * dy * t01 + dy * dy * t00) * inv_dt;
    float tr = (t11 * p00 + t00 * p11 - 2.0f * t01 * p01) * inv_dt;
    float term2 = tr + __logf(dt * inv_dp);
    float dis = term1 + term2 - 2.0f;
    float kl = fmaxf(dis, 1e-6f);
    float l1p = __logf(1.0f + kl);
    return 1.0f - __builtin_amdgcn_rcpf(TAU_CONST + l1p);
}

// ---------------- round-2 structure + NON-TEMPORAL cache policy ----------------
// Identical to the 62.3 us LDS-staged kernel, except:
//   - global_load_lds aux = 2 (NT cpol bit: evict-first in L2/L3)
//   - output stores via __builtin_nontemporal_store (ext_vector_type, not HIP float2)
// Probe: if L3 allocation churn is the ~2.8 TB/s serializer, this collapses it.

__device__ __forceinline__ void gload_lds16_nt(const void* g, void* l) {
    __builtin_amdgcn_global_load_lds((const __attribute__((address_space(1))) uint32_t*)g,
                                     (__attribute__((address_space(3))) uint32_t*)l,
                                     16, 0, /*aux: NT*/ 2);
}

__global__ void __launch_bounds__(256, 8) gdloss_lds_kernel(const float* __restrict__ pred,
                                                            const float* __restrict__ target,
                                                            float* __restrict__ out) {
    __shared__ float lds[5120];  // [0,2560): pred rows, [2560,5120): target rows
    const int tid = threadIdx.x;
    const int wv  = tid >> 6;
    const int ln  = tid & 63;
    const long long base = (long long)blockIdx.x * 2560;  // floats: 512 rows * 5

#pragma unroll
    for (int k = 0; k < 5; ++k) {
        int c = wv * 5 + k;                       // 0..19, wave-uniform
        const float* g = (c < 10) ? (pred   + base + c * 256 + ln * 4)
                                  : (target + base + (c - 10) * 256 + ln * 4);
        gload_lds16_nt(g, &lds[c * 256]);         // lane l lands at +16B*l (linear mirror)
    }
    __syncthreads();

    // rows 2*tid and 2*tid+1: 10 consecutive floats at float index 10*tid (8-B aligned)
    const float2* lp = (const float2*)&lds[10 * tid];
    const float2* lt = (const float2*)&lds[2560 + 10 * tid];
    float2 p0 = lp[0], p1 = lp[1], p2 = lp[2], p3 = lp[3], p4 = lp[4];
    float2 t0 = lt[0], t1 = lt[1], t2 = lt[2], t3 = lt[3], t4 = lt[4];

    float pr0[5] = {p0.x, p0.y, p1.x, p1.y, p2.x};
    float pr1[5] = {p2.y, p3.x, p3.y, p4.x, p4.y};
    float tr0[5] = {t0.x, t0.y, t1.x, t1.y, t2.x};
    float tr1[5] = {t2.y, t3.x, t3.y, t4.x, t4.y};

    v2f o;
    o.x = kld_row(pr0, tr0);
    o.y = kld_row(pr1, tr1);
    __builtin_nontemporal_store(o, (v2f*)out + (size_t)blockIdx.x * 256 + tid);
}

// Scalar tail (rows not covered by full 512-row tiles).
__global__ void gdloss_tail_kernel(const float* __restrict__ pred,
                                   const float* __restrict__ target,
                                   float* __restrict__ out, int start, int n) {
    int i = start + blockIdx.x * blockDim.x + threadIdx.x;
    if (i >= n) return;
    float p[5], t[5];
#pragma unroll
    for (int k = 0; k < 5; ++k) {
        p[k] = pred[5 * i + k];
        t[k] = target[5 * i + k];
    }
    out[i] = kld_row(p, t);
}

extern "C" void kernel_launch(void* const* d_in, const int* in_sizes, int n_in,
                              void* d_out, int out_size, void* d_ws, size_t ws_size,
                              hipStream_t stream) {
    const float* pred   = (const float*)d_in[0];
    const float* target = (const float*)d_in[1];
    float* out = (float*)d_out;
    int n  = in_sizes[0] / 5;     // number of rows
    int nb = n / 512;             // full 512-row tiles
    if (nb > 0) {
        gdloss_lds_kernel<<<nb, 256, 0, stream>>>(pred, target, out);
    }
    int start = nb * 512;
    int rem = n - start;
    if (rem > 0) {
        int tb = (rem + 255) / 256;
        gdloss_tail_kernel<<<tb, 256, 0, stream>>>(pred, target, out, start, n);
    }
}

// Round 6
// 166.044 us; speedup vs baseline: 1.0866x; 1.0154x over previous
//
#include <hip/hip_runtime.h>
#include <math.h>
#include <stdint.h>

#ifndef TAU_CONST
#define TAU_CONST 1.0f
#endif

// ---------------- math (unchanged) ----------------

__device__ __forceinline__ void rbox_to_gauss(float x, float y, float w, float h, float r,
                                              float& mx, float& my,
                                              float& s00, float& s01, float& s11, float& det) {
    w = fminf(fmaxf(w, 1e-7f), 1e7f);
    h = fminf(fmaxf(h, 1e-7f), 1e7f);
    float a = 0.25f * w * w;   // (w/2)^2
    float b = 0.25f * h * h;   // (h/2)^2
    float s2, c2;
    __sincosf(r + r, &s2, &c2);          // sin 2r, cos 2r
    float hs = 0.5f * (a + b);
    float hd = 0.5f * (a - b);
    s00 = fmaf(hd, c2, hs);
    s11 = fmaf(-hd, c2, hs);
    s01 = hd * s2;
    det = a * b;                          // det(R S R^T) == a*b exactly
    mx = x; my = y;
}

__device__ __forceinline__ float kld_row(const float* p, const float* t) {
    float pmx, pmy, p00, p01, p11, dp;
    float tmx, tmy, t00, t01, t11, dt;
    rbox_to_gauss(p[0], p[1], p[2], p[3], p[4], pmx, pmy, p00, p01, p11, dp);
    rbox_to_gauss(t[0], t[1], t[2], t[3], t[4], tmx, tmy, t00, t01, t11, dt);
    float dx = pmx - tmx, dy = pmy - tmy;
    float inv_dt = __builtin_amdgcn_rcpf(dt);
    float inv_dp = __builtin_amdgcn_rcpf(dp);
    float term1 = (dx * dx * t11 - 2.0f * dx * dy * t01 + dy * dy * t00) * inv_dt;
    float tr = (t11 * p00 + t00 * p11 - 2.0f * t01 * p01) * inv_dt;
    float term2 = tr + __logf(dt * inv_dp);
    float dis = term1 + term2 - 2.0f;
    float kl = fmaxf(dis, 1e-6f);
    float l1p = __logf(1.0f + kl);
    return 1.0f - __builtin_amdgcn_rcpf(TAU_CONST + l1p);
}

// ------- persistent double-buffered pipeline (round 3) + NT policy (round 5) -------
// 2048 blocks (8/CU) grid-stride over 256-row tiles; LDS 2 x 10 KB = 20 KB.
// All input traffic: global_load_lds width=16 with aux=2 (NT, evict-first in L2/L3).
// Output: nontemporal scalar store. NT collapsed the L3-allocation serializer
// (round 5: 62 -> ~52 us); the pipeline keeps ~10 KB/block in flight continuously
// instead of draining vmcnt(0) and idling each generation.

__device__ __forceinline__ void gload_lds16_nt(const void* g, void* l) {
    __builtin_amdgcn_global_load_lds((const __attribute__((address_space(1))) uint32_t*)g,
                                     (__attribute__((address_space(3))) uint32_t*)l,
                                     16, 0, /*aux: NT*/ 2);
}

#define ROWS_PER_TILE 256
#define FLOATS_PER_TILE (ROWS_PER_TILE * 5)   // 1280 floats per input per tile

__global__ void __launch_bounds__(256, 8)
gdloss_pipe_kernel(const float* __restrict__ pred,
                   const float* __restrict__ target,
                   float* __restrict__ out, int ntiles) {
    __shared__ float lds[2][2 * FLOATS_PER_TILE];  // [buf][pred 1280 | tgt 1280]
    const int tid = threadIdx.x;
    const int wv  = tid >> 6;
    const int ln  = tid & 63;
    const int stride = gridDim.x;

    int t = blockIdx.x;
    // prologue: stage first tile into buf 0
    if (t < ntiles) {
        for (int c = wv; c < 10; c += 4) {   // chunk c: c<5 pred, c>=5 tgt
            const float* g = (c < 5)
                ? (pred   + (long long)t * FLOATS_PER_TILE + c * 256 + ln * 4)
                : (target + (long long)t * FLOATS_PER_TILE + (c - 5) * 256 + ln * 4);
            gload_lds16_nt(g, &lds[0][c * 256]);
        }
    }

    int buf = 0;
    for (; t < ntiles; t += stride) {
        __syncthreads();                     // tile t staged (vmcnt drain + barrier)
        int tn = t + stride;
        if (tn < ntiles) {                   // issue next tile into buf^1, overlaps compute
            for (int c = wv; c < 10; c += 4) {
                const float* g = (c < 5)
                    ? (pred   + (long long)tn * FLOATS_PER_TILE + c * 256 + ln * 4)
                    : (target + (long long)tn * FLOATS_PER_TILE + (c - 5) * 256 + ln * 4);
                gload_lds16_nt(g, &lds[buf ^ 1][c * 256]);
            }
        }
        // compute tile t: one row/thread, 5 consecutive floats at 5*tid
        // bank = (5*lane + k) mod 32, gcd(5,32)=1 -> 2 lanes/bank = free
        const float* lp = &lds[buf][5 * tid];
        const float* lt = &lds[buf][FLOATS_PER_TILE + 5 * tid];
        float p[5], tt[5];
#pragma unroll
        for (int k = 0; k < 5; ++k) { p[k] = lp[k]; tt[k] = lt[k]; }
        float r = kld_row(p, tt);
        __builtin_nontemporal_store(r, &out[(long long)t * ROWS_PER_TILE + tid]);
        buf ^= 1;
    }
}

// Scalar tail (rows not covered by full tiles; none at N=4M).
__global__ void gdloss_tail_kernel(const float* __restrict__ pred,
                                   const float* __restrict__ target,
                                   float* __restrict__ out, int start, int n) {
    int i = start + blockIdx.x * blockDim.x + threadIdx.x;
    if (i >= n) return;
    float p[5], t[5];
#pragma unroll
    for (int k = 0; k < 5; ++k) {
        p[k] = pred[5 * i + k];
        t[k] = target[5 * i + k];
    }
    out[i] = kld_row(p, t);
}

extern "C" void kernel_launch(void* const* d_in, const int* in_sizes, int n_in,
                              void* d_out, int out_size, void* d_ws, size_t ws_size,
                              hipStream_t stream) {
    const float* pred   = (const float*)d_in[0];
    const float* target = (const float*)d_in[1];
    float* out = (float*)d_out;
    int n      = in_sizes[0] / 5;          // rows
    int ntiles = n / ROWS_PER_TILE;
    if (ntiles > 0) {
        int blocks = ntiles < 2048 ? ntiles : 2048;   // 8 blocks/CU, persistent
        gdloss_pipe_kernel<<<blocks, 256, 0, stream>>>(pred, target, out, ntiles);
    }
    int start = ntiles * ROWS_PER_TILE;
    int rem = n - start;
    if (rem > 0) {
        int tb = (rem + 255) / 256;
        gdloss_tail_kernel<<<tb, 256, 0, stream>>>(pred, target, out, start, n);
    }
}